// Round 1
// baseline (1199.324 us; speedup 1.0000x reference)
//
#include <hip/hip_runtime.h>

// Problem: FastformerAttention  B=32, N=4096, DIM=512, DD=512
// out = (gk ⊙ v) @ Wr + q, with gq/gk additive-attention pools.
//
// Pipeline:
//   prep_w    : Wt[1536][512] = bf16([Wq|Wk|Wv]^T)   (B^T layout for MFMA)
//   gemm_qkv  : qkv[131072][1536] bf16 = x @ [Wq|Wk|Wv]   (A fp32 inline-cvt, B async)
//   pool_alpha: gq[b][512] = sum_n q*softmax_d(q*alpha*SCALE)
//   pool_beta : gk[b][512] = sum_n p*softmax_d(p*beta*SCALE), p = gq⊙k
//   build_wrs : Wrs[b][e][d] = bf16(gk[b][d]*Wr[d][e])     (B^T layout)
//   gemm_out  : out[b][n][e] = v[b] @ Wrs_b^T + q  (fp32 out)

typedef __attribute__((ext_vector_type(8))) short short8;
typedef __attribute__((ext_vector_type(4))) float floatx4;
typedef __attribute__((ext_vector_type(2))) unsigned int u32x2;
typedef unsigned short u16;
typedef unsigned int u32;

#define SEQ 4096
#define BATCH 32
#define DMODEL 512
#define NQKV 1536
#define FSCALE 0.044194173824159216f  // 512^-0.5

__device__ __forceinline__ u16 f2bf(float f) {
  u32 u = __float_as_uint(f);
  u += 0x7fffu + ((u >> 16) & 1u);  // RNE
  return (u16)(u >> 16);
}
__device__ __forceinline__ float bf2f(u16 h) { return __uint_as_float((u32)h << 16); }

__device__ __forceinline__ void g2l16(const void* g, void* l) {
  __builtin_amdgcn_global_load_lds(
      (const __attribute__((address_space(1))) void*)g,
      (__attribute__((address_space(3))) void*)l, 16, 0, 0);
}

// ---------------- prep: transpose+convert weights ----------------
__global__ void prep_w(const float* __restrict__ Wq, const float* __restrict__ Wk,
                       const float* __restrict__ Wv, u16* __restrict__ Wt) {
  int n = blockIdx.x;  // 0..1535  (output column)
  const float* W = (n < 512) ? Wq : ((n < 1024) ? Wk : Wv);
  int col = n & 511;
  for (int kk = threadIdx.x; kk < 512; kk += 256)
    Wt[(size_t)n * 512 + kk] = f2bf(W[(size_t)kk * 512 + col]);
}

// ---------------- GEMM: qkv = x @ Wqkv (bf16 out) ----------------
// 128x128 tile, BK=32, 4 waves in 2x2, 16x16x32 MFMA, 4x4 acc per wave.
__global__ __launch_bounds__(256) void gemm_qkv(const float* __restrict__ x,
                                                const u16* __restrict__ Wt,
                                                u16* __restrict__ qkv) {
  __shared__ u16 sA[128 * 32];
  __shared__ u16 sB[128 * 32];
  const int tid = threadIdx.x;
  const int lane = tid & 63, wv = tid >> 6;
  const int row0 = blockIdx.y * 128;   // M tile (131072 rows)
  const int col0 = blockIdx.x * 128;   // N tile (1536 cols)
  const int wm = (wv >> 1) * 64, wn = (wv & 1) * 64;

  floatx4 acc[4][4] = {};

  const int ln = lane & 15;
  const int quad = (lane >> 4);
  const int b_row = (lane >> 2);        // staging: row within 16-row chunk
  const int b_kq = (lane & 3) * 8;      // staging: k offset (8 bf16 = 16B)

  for (int kt = 0; kt < 16; ++kt) {
    const int k0 = kt * 32;
    __syncthreads();  // previous iter's LDS reads done
    // A stage: fp32 -> bf16, 4 float4 per thread
#pragma unroll
    for (int c = 0; c < 4; ++c) {
      int lin = c * 256 + tid;
      int r = lin >> 3, kq = (lin & 7) * 4;
      const float4 f = *(const float4*)(x + (size_t)(row0 + r) * 512 + k0 + kq);
      u32x2 pv;
      pv.x = (u32)f2bf(f.x) | ((u32)f2bf(f.y) << 16);
      pv.y = (u32)f2bf(f.z) | ((u32)f2bf(f.w) << 16);
      *(u32x2*)(sA + r * 32 + kq) = pv;
    }
    // B stage: async 16B direct-to-LDS, 2 chunks per wave
#pragma unroll
    for (int c = 0; c < 2; ++c) {
      int chunk = wv * 2 + c;
      int r = chunk * 16 + b_row;
      g2l16(Wt + (size_t)(col0 + r) * 512 + k0 + b_kq, sB + chunk * 512 + lane * 8);
    }
    __syncthreads();  // drains vmcnt+lgkmcnt

    short8 a[4], b[4];
#pragma unroll
    for (int i = 0; i < 4; ++i)
      a[i] = *(const short8*)&sA[(wm + i * 16 + ln) * 32 + quad * 8];
#pragma unroll
    for (int j = 0; j < 4; ++j)
      b[j] = *(const short8*)&sB[(wn + j * 16 + ln) * 32 + quad * 8];
#pragma unroll
    for (int i = 0; i < 4; ++i)
#pragma unroll
      for (int j = 0; j < 4; ++j)
        acc[i][j] = __builtin_amdgcn_mfma_f32_16x16x32_bf16(a[i], b[j], acc[i][j], 0, 0, 0);
  }

  // epilogue: bf16 store. D: col = lane&15, row = quad*4 + reg
#pragma unroll
  for (int i = 0; i < 4; ++i) {
#pragma unroll
    for (int r = 0; r < 4; ++r) {
      int grow = row0 + wm + i * 16 + quad * 4 + r;
      size_t base = (size_t)grow * NQKV + col0 + wn + ln;
#pragma unroll
      for (int j = 0; j < 4; ++j)
        qkv[base + j * 16] = f2bf(acc[i][j][r]);
    }
  }
}

// ---------------- pools: per-row softmax over d, sum over n ----------------
// one wave per row; lane l owns d = l*8 .. l*8+7
__global__ __launch_bounds__(256) void pool_alpha(const u16* __restrict__ qkv,
                                                  const float* __restrict__ alpha,
                                                  float* __restrict__ gq) {
  const int b = blockIdx.y;
  const int lane = threadIdx.x & 63, wv = threadIdx.x >> 6;
  const int slot = blockIdx.x * 4 + wv;  // 0..63
  float a8[8], acc8[8];
#pragma unroll
  for (int j = 0; j < 8; ++j) {
    a8[j] = alpha[lane * 8 + j] * FSCALE;
    acc8[j] = 0.f;
  }
  for (int i = 0; i < 64; ++i) {
    int row = slot * 64 + i;
    const u16* qr = qkv + (size_t)(b * SEQ + row) * NQKV + lane * 8;
    short8 s = *(const short8*)qr;
    float q[8], t[8];
    float m = -1e30f;
#pragma unroll
    for (int j = 0; j < 8; ++j) {
      q[j] = bf2f((u16)s[j]);
      t[j] = q[j] * a8[j];
      m = fmaxf(m, t[j]);
    }
#pragma unroll
    for (int off = 32; off >= 1; off >>= 1) m = fmaxf(m, __shfl_xor(m, off));
    float sum = 0.f;
    float e[8];
#pragma unroll
    for (int j = 0; j < 8; ++j) {
      e[j] = __expf(t[j] - m);
      sum += e[j];
    }
#pragma unroll
    for (int off = 32; off >= 1; off >>= 1) sum += __shfl_xor(sum, off);
    float inv = 1.f / sum;
#pragma unroll
    for (int j = 0; j < 8; ++j) acc8[j] += q[j] * e[j] * inv;
  }
#pragma unroll
  for (int j = 0; j < 8; ++j) atomicAdd(&gq[b * 512 + lane * 8 + j], acc8[j]);
}

__global__ __launch_bounds__(256) void pool_beta(const u16* __restrict__ qkv,
                                                 const float* __restrict__ beta,
                                                 const float* __restrict__ gq,
                                                 float* __restrict__ gk) {
  const int b = blockIdx.y;
  const int lane = threadIdx.x & 63, wv = threadIdx.x >> 6;
  const int slot = blockIdx.x * 4 + wv;
  float b8[8], g8[8], acc8[8];
#pragma unroll
  for (int j = 0; j < 8; ++j) {
    b8[j] = beta[lane * 8 + j] * FSCALE;
    g8[j] = gq[b * 512 + lane * 8 + j];
    acc8[j] = 0.f;
  }
  for (int i = 0; i < 64; ++i) {
    int row = slot * 64 + i;
    const u16* kr = qkv + (size_t)(b * SEQ + row) * NQKV + 512 + lane * 8;
    short8 s = *(const short8*)kr;
    float p[8], t[8];
    float m = -1e30f;
#pragma unroll
    for (int j = 0; j < 8; ++j) {
      p[j] = g8[j] * bf2f((u16)s[j]);
      t[j] = p[j] * b8[j];
      m = fmaxf(m, t[j]);
    }
#pragma unroll
    for (int off = 32; off >= 1; off >>= 1) m = fmaxf(m, __shfl_xor(m, off));
    float sum = 0.f;
    float e[8];
#pragma unroll
    for (int j = 0; j < 8; ++j) {
      e[j] = __expf(t[j] - m);
      sum += e[j];
    }
#pragma unroll
    for (int off = 32; off >= 1; off >>= 1) sum += __shfl_xor(sum, off);
    float inv = 1.f / sum;
#pragma unroll
    for (int j = 0; j < 8; ++j) acc8[j] += p[j] * e[j] * inv;
  }
#pragma unroll
  for (int j = 0; j < 8; ++j) atomicAdd(&gk[b * 512 + lane * 8 + j], acc8[j]);
}

// ---------------- fold gk into Wr (B^T layout) ----------------
__global__ void build_wrs(const float* __restrict__ Wr, const float* __restrict__ gk,
                          u16* __restrict__ Wrs) {
  int e = blockIdx.x, b = blockIdx.y;
  const float* g = gk + b * 512;
  u16* o = Wrs + ((size_t)b * 512 + e) * 512;
  for (int d = threadIdx.x; d < 512; d += 256)
    o[d] = f2bf(g[d] * Wr[(size_t)d * 512 + e]);
}

// ---------------- GEMM: out = v @ Wrs_b^T + q (fp32 out) ----------------
__global__ __launch_bounds__(256) void gemm_out(const u16* __restrict__ qkv,
                                                const u16* __restrict__ Wrs,
                                                float* __restrict__ out) {
  __shared__ u16 sA[128 * 32];
  __shared__ u16 sB[128 * 32];
  const int tid = threadIdx.x;
  const int lane = tid & 63, wv = tid >> 6;
  const int b = blockIdx.z;
  const int row0 = blockIdx.y * 128;  // 0..4095
  const int col0 = blockIdx.x * 128;  // 0..511
  const int wm = (wv >> 1) * 64, wn = (wv & 1) * 64;

  floatx4 acc[4][4] = {};
  const int ln = lane & 15;
  const int quad = (lane >> 4);
  const int b_row = (lane >> 2);
  const int b_kq = (lane & 3) * 8;

  const u16* vbase = qkv + (size_t)b * SEQ * NQKV + 1024;
  const u16* wbase = Wrs + (size_t)b * 512 * 512;

  for (int kt = 0; kt < 16; ++kt) {
    const int k0 = kt * 32;
    __syncthreads();
#pragma unroll
    for (int c = 0; c < 2; ++c) {
      int chunk = wv * 2 + c;
      int r = chunk * 16 + b_row;
      g2l16(vbase + (size_t)(row0 + r) * NQKV + k0 + b_kq, sA + chunk * 512 + lane * 8);
      g2l16(wbase + (size_t)(col0 + r) * 512 + k0 + b_kq, sB + chunk * 512 + lane * 8);
    }
    __syncthreads();

    short8 a[4], bb[4];
#pragma unroll
    for (int i = 0; i < 4; ++i)
      a[i] = *(const short8*)&sA[(wm + i * 16 + ln) * 32 + quad * 8];
#pragma unroll
    for (int j = 0; j < 4; ++j)
      bb[j] = *(const short8*)&sB[(wn + j * 16 + ln) * 32 + quad * 8];
#pragma unroll
    for (int i = 0; i < 4; ++i)
#pragma unroll
      for (int j = 0; j < 4; ++j)
        acc[i][j] = __builtin_amdgcn_mfma_f32_16x16x32_bf16(a[i], bb[j], acc[i][j], 0, 0, 0);
  }

#pragma unroll
  for (int i = 0; i < 4; ++i) {
#pragma unroll
    for (int r = 0; r < 4; ++r) {
      int grow = row0 + wm + i * 16 + quad * 4 + r;
      size_t qrow = (size_t)(b * SEQ + grow) * NQKV;
      size_t orow = (size_t)(b * SEQ + grow) * 512;
#pragma unroll
      for (int j = 0; j < 4; ++j) {
        int gcol = col0 + wn + ln + j * 16;
        float qv = bf2f(qkv[qrow + gcol]);
        out[orow + gcol] = acc[i][j][r] + qv;
      }
    }
  }
}

// ---------------- launcher ----------------
extern "C" void kernel_launch(void* const* d_in, const int* in_sizes, int n_in,
                              void* d_out, int out_size, void* d_ws, size_t ws_size,
                              hipStream_t stream) {
  const float* x = (const float*)d_in[0];
  const float* Wq = (const float*)d_in[1];
  const float* Wk = (const float*)d_in[2];
  const float* Wv = (const float*)d_in[3];
  const float* Wr = (const float*)d_in[4];
  const float* alpha = (const float*)d_in[5];
  const float* beta = (const float*)d_in[6];
  float* out = (float*)d_out;

  char* ws = (char*)d_ws;
  // layout (bytes): qkv 402,653,184 | Wt 1,572,864 | Wrs 16,777,216 | gq 64K | gk 64K
  u16* qkv = (u16*)ws;
  u16* Wt = (u16*)(ws + 402653184ull);
  u16* Wrs = (u16*)(ws + 402653184ull + 1572864ull);
  float* gq = (float*)(ws + 402653184ull + 1572864ull + 16777216ull);
  float* gk = gq + 16384;

  hipMemsetAsync(gq, 0, 131072, stream);  // gq+gk
  prep_w<<<1536, 256, 0, stream>>>(Wq, Wk, Wv, Wt);
  gemm_qkv<<<dim3(12, 1024), 256, 0, stream>>>(x, Wt, qkv);
  pool_alpha<<<dim3(16, BATCH), 256, 0, stream>>>(qkv, alpha, gq);
  pool_beta<<<dim3(16, BATCH), 256, 0, stream>>>(qkv, beta, gq, gk);
  build_wrs<<<dim3(512, BATCH), 256, 0, stream>>>(Wr, gk, Wrs);
  gemm_out<<<dim3(4, 32, BATCH), 256, 0, stream>>>(qkv, Wrs, out);
}

// Round 2
// 1162.765 us; speedup vs baseline: 1.0314x; 1.0314x over previous
//
#include <hip/hip_runtime.h>

// Problem: FastformerAttention  B=32, N=4096, DIM=512, DD=512
//
// Pipeline (R2: x converted to bf16 upfront; gemm_qkv = pure m97 async structure):
//   convert_x : x_bf16[131072][512] = bf16(x)            (stored in d_out scratch)
//   prep_w    : Wt[1536][512] = bf16([Wq|Wk|Wv]^T)       (B^T layout for MFMA)
//   gemm_qkv  : qkv[131072][1536] bf16 = x_bf16 @ Wt^T   (both operands async g2l16)
//   pool_alpha: gq[b][512] = sum_n q*softmax_d(q*alpha*SCALE)
//   pool_beta : gk[b][512] = sum_n p*softmax_d(p*beta*SCALE), p = gq⊙k
//   build_wrs : Wrs[b][e][d] = bf16(gk[b][d]*Wr[d][e])   (B^T layout)
//   gemm_out  : out[b][n][e] = v[b] @ Wrs_b^T + q        (fp32 out, overwrites scratch)

typedef __attribute__((ext_vector_type(8))) short short8;
typedef __attribute__((ext_vector_type(4))) float floatx4;
typedef unsigned short u16;
typedef unsigned int u32;

#define SEQ 4096
#define BATCH 32
#define NQKV 1536
#define FSCALE 0.044194173824159216f  // 512^-0.5

__device__ __forceinline__ u16 f2bf(float f) {
  u32 u = __float_as_uint(f);
  u += 0x7fffu + ((u >> 16) & 1u);  // RNE
  return (u16)(u >> 16);
}
__device__ __forceinline__ float bf2f(u16 h) { return __uint_as_float((u32)h << 16); }

__device__ __forceinline__ void g2l16(const void* g, void* l) {
  __builtin_amdgcn_global_load_lds(
      (const __attribute__((address_space(1))) void*)g,
      (__attribute__((address_space(3))) void*)l, 16, 0, 0);
}

// ---------------- convert x: fp32 -> bf16, straight elementwise ----------------
__global__ __launch_bounds__(256) void convert_x(const float* __restrict__ x,
                                                 u16* __restrict__ xb) {
  size_t i = ((size_t)blockIdx.x * 256 + threadIdx.x) * 8;
  float4 f0 = *(const float4*)(x + i);
  float4 f1 = *(const float4*)(x + i + 4);
  short8 s;
  s[0] = (short)f2bf(f0.x); s[1] = (short)f2bf(f0.y);
  s[2] = (short)f2bf(f0.z); s[3] = (short)f2bf(f0.w);
  s[4] = (short)f2bf(f1.x); s[5] = (short)f2bf(f1.y);
  s[6] = (short)f2bf(f1.z); s[7] = (short)f2bf(f1.w);
  *(short8*)(xb + i) = s;
}

// ---------------- prep: transpose+convert weights ----------------
__global__ void prep_w(const float* __restrict__ Wq, const float* __restrict__ Wk,
                       const float* __restrict__ Wv, u16* __restrict__ Wt) {
  int n = blockIdx.x;  // 0..1535  (output column)
  const float* W = (n < 512) ? Wq : ((n < 1024) ? Wk : Wv);
  int col = n & 511;
  for (int kk = threadIdx.x; kk < 512; kk += 256)
    Wt[(size_t)n * 512 + kk] = f2bf(W[(size_t)kk * 512 + col]);
}

// ---------------- GEMM: qkv = x_bf16 @ Wt^T (bf16 out), m97 structure ----------------
__global__ __launch_bounds__(256) void gemm_qkv(const u16* __restrict__ xb,
                                                const u16* __restrict__ Wt,
                                                u16* __restrict__ qkv) {
  __shared__ u16 sA[128 * 32];
  __shared__ u16 sB[128 * 32];
  const int tid = threadIdx.x;
  const int lane = tid & 63, wv = tid >> 6;
  const int row0 = blockIdx.y * 128;   // M tile (131072 rows)
  const int col0 = blockIdx.x * 128;   // N tile (1536 cols)
  const int wm = (wv >> 1) * 64, wn = (wv & 1) * 64;

  floatx4 acc[4][4] = {};
  const int ln = lane & 15;
  const int quad = (lane >> 4);
  const int b_row = (lane >> 2);   // staging: row within 16-row chunk
  const int b_kq = (lane & 3) * 8; // staging: k offset (8 bf16 = 16B)

  for (int kt = 0; kt < 16; ++kt) {
    const int k0 = kt * 32;
    __syncthreads();
#pragma unroll
    for (int c = 0; c < 2; ++c) {
      int chunk = wv * 2 + c;
      int r = chunk * 16 + b_row;
      g2l16(xb + (size_t)(row0 + r) * 512 + k0 + b_kq, sA + chunk * 512 + lane * 8);
      g2l16(Wt + (size_t)(col0 + r) * 512 + k0 + b_kq, sB + chunk * 512 + lane * 8);
    }
    __syncthreads();

    short8 a[4], b[4];
#pragma unroll
    for (int i = 0; i < 4; ++i)
      a[i] = *(const short8*)&sA[(wm + i * 16 + ln) * 32 + quad * 8];
#pragma unroll
    for (int j = 0; j < 4; ++j)
      b[j] = *(const short8*)&sB[(wn + j * 16 + ln) * 32 + quad * 8];
#pragma unroll
    for (int i = 0; i < 4; ++i)
#pragma unroll
      for (int j = 0; j < 4; ++j)
        acc[i][j] = __builtin_amdgcn_mfma_f32_16x16x32_bf16(a[i], b[j], acc[i][j], 0, 0, 0);
  }

  // epilogue: bf16 store. D: col = lane&15, row = quad*4 + reg
#pragma unroll
  for (int i = 0; i < 4; ++i) {
#pragma unroll
    for (int r = 0; r < 4; ++r) {
      int grow = row0 + wm + i * 16 + quad * 4 + r;
      size_t base = (size_t)grow * NQKV + col0 + wn + ln;
#pragma unroll
      for (int j = 0; j < 4; ++j)
        qkv[base + j * 16] = f2bf(acc[i][j][r]);
    }
  }
}

// ---------------- pools: per-row softmax over d, sum over n ----------------
__global__ __launch_bounds__(256) void pool_alpha(const u16* __restrict__ qkv,
                                                  const float* __restrict__ alpha,
                                                  float* __restrict__ gq) {
  const int b = blockIdx.y;
  const int lane = threadIdx.x & 63, wv = threadIdx.x >> 6;
  const int slot = blockIdx.x * 4 + wv;  // 0..63
  float a8[8], acc8[8];
#pragma unroll
  for (int j = 0; j < 8; ++j) {
    a8[j] = alpha[lane * 8 + j] * FSCALE;
    acc8[j] = 0.f;
  }
  for (int i = 0; i < 64; ++i) {
    int row = slot * 64 + i;
    const u16* qr = qkv + (size_t)(b * SEQ + row) * NQKV + lane * 8;
    short8 s = *(const short8*)qr;
    float q[8], t[8];
    float m = -1e30f;
#pragma unroll
    for (int j = 0; j < 8; ++j) {
      q[j] = bf2f((u16)s[j]);
      t[j] = q[j] * a8[j];
      m = fmaxf(m, t[j]);
    }
#pragma unroll
    for (int off = 32; off >= 1; off >>= 1) m = fmaxf(m, __shfl_xor(m, off));
    float sum = 0.f;
    float e[8];
#pragma unroll
    for (int j = 0; j < 8; ++j) {
      e[j] = __expf(t[j] - m);
      sum += e[j];
    }
#pragma unroll
    for (int off = 32; off >= 1; off >>= 1) sum += __shfl_xor(sum, off);
    float inv = 1.f / sum;
#pragma unroll
    for (int j = 0; j < 8; ++j) acc8[j] += q[j] * e[j] * inv;
  }
#pragma unroll
  for (int j = 0; j < 8; ++j) atomicAdd(&gq[b * 512 + lane * 8 + j], acc8[j]);
}

__global__ __launch_bounds__(256) void pool_beta(const u16* __restrict__ qkv,
                                                 const float* __restrict__ beta,
                                                 const float* __restrict__ gq,
                                                 float* __restrict__ gk) {
  const int b = blockIdx.y;
  const int lane = threadIdx.x & 63, wv = threadIdx.x >> 6;
  const int slot = blockIdx.x * 4 + wv;
  float b8[8], g8[8], acc8[8];
#pragma unroll
  for (int j = 0; j < 8; ++j) {
    b8[j] = beta[lane * 8 + j] * FSCALE;
    g8[j] = gq[b * 512 + lane * 8 + j];
    acc8[j] = 0.f;
  }
  for (int i = 0; i < 64; ++i) {
    int row = slot * 64 + i;
    const u16* kr = qkv + (size_t)(b * SEQ + row) * NQKV + 512 + lane * 8;
    short8 s = *(const short8*)kr;
    float p[8], t[8];
    float m = -1e30f;
#pragma unroll
    for (int j = 0; j < 8; ++j) {
      p[j] = g8[j] * bf2f((u16)s[j]);
      t[j] = p[j] * b8[j];
      m = fmaxf(m, t[j]);
    }
#pragma unroll
    for (int off = 32; off >= 1; off >>= 1) m = fmaxf(m, __shfl_xor(m, off));
    float sum = 0.f;
    float e[8];
#pragma unroll
    for (int j = 0; j < 8; ++j) {
      e[j] = __expf(t[j] - m);
      sum += e[j];
    }
#pragma unroll
    for (int off = 32; off >= 1; off >>= 1) sum += __shfl_xor(sum, off);
    float inv = 1.f / sum;
#pragma unroll
    for (int j = 0; j < 8; ++j) acc8[j] += p[j] * e[j] * inv;
  }
#pragma unroll
  for (int j = 0; j < 8; ++j) atomicAdd(&gk[b * 512 + lane * 8 + j], acc8[j]);
}

// ---------------- fold gk into Wr (B^T layout) ----------------
__global__ void build_wrs(const float* __restrict__ Wr, const float* __restrict__ gk,
                          u16* __restrict__ Wrs) {
  int e = blockIdx.x, b = blockIdx.y;
  const float* g = gk + b * 512;
  u16* o = Wrs + ((size_t)b * 512 + e) * 512;
  for (int d = threadIdx.x; d < 512; d += 256)
    o[d] = f2bf(g[d] * Wr[(size_t)d * 512 + e]);
}

// ---------------- GEMM: out = v @ Wrs_b^T + q (fp32 out) ----------------
__global__ __launch_bounds__(256) void gemm_out(const u16* __restrict__ qkv,
                                                const u16* __restrict__ Wrs,
                                                float* __restrict__ out) {
  __shared__ u16 sA[128 * 32];
  __shared__ u16 sB[128 * 32];
  const int tid = threadIdx.x;
  const int lane = tid & 63, wv = tid >> 6;
  const int b = blockIdx.z;
  const int row0 = blockIdx.y * 128;  // 0..4095
  const int col0 = blockIdx.x * 128;  // 0..511
  const int wm = (wv >> 1) * 64, wn = (wv & 1) * 64;

  floatx4 acc[4][4] = {};
  const int ln = lane & 15;
  const int quad = (lane >> 4);
  const int b_row = (lane >> 2);
  const int b_kq = (lane & 3) * 8;

  const u16* vbase = qkv + (size_t)b * SEQ * NQKV + 1024;
  const u16* wbase = Wrs + (size_t)b * 512 * 512;

  for (int kt = 0; kt < 16; ++kt) {
    const int k0 = kt * 32;
    __syncthreads();
#pragma unroll
    for (int c = 0; c < 2; ++c) {
      int chunk = wv * 2 + c;
      int r = chunk * 16 + b_row;
      g2l16(vbase + (size_t)(row0 + r) * NQKV + k0 + b_kq, sA + chunk * 512 + lane * 8);
      g2l16(wbase + (size_t)(col0 + r) * 512 + k0 + b_kq, sB + chunk * 512 + lane * 8);
    }
    __syncthreads();

    short8 a[4], bb[4];
#pragma unroll
    for (int i = 0; i < 4; ++i)
      a[i] = *(const short8*)&sA[(wm + i * 16 + ln) * 32 + quad * 8];
#pragma unroll
    for (int j = 0; j < 4; ++j)
      bb[j] = *(const short8*)&sB[(wn + j * 16 + ln) * 32 + quad * 8];
#pragma unroll
    for (int i = 0; i < 4; ++i)
#pragma unroll
      for (int j = 0; j < 4; ++j)
        acc[i][j] = __builtin_amdgcn_mfma_f32_16x16x32_bf16(a[i], bb[j], acc[i][j], 0, 0, 0);
  }

#pragma unroll
  for (int i = 0; i < 4; ++i) {
#pragma unroll
    for (int r = 0; r < 4; ++r) {
      int grow = row0 + wm + i * 16 + quad * 4 + r;
      size_t qrow = (size_t)(b * SEQ + grow) * NQKV;
      size_t orow = (size_t)(b * SEQ + grow) * 512;
#pragma unroll
      for (int j = 0; j < 4; ++j) {
        int gcol = col0 + wn + ln + j * 16;
        float qv = bf2f(qkv[qrow + gcol]);
        out[orow + gcol] = acc[i][j][r] + qv;
      }
    }
  }
}

// ---------------- launcher ----------------
extern "C" void kernel_launch(void* const* d_in, const int* in_sizes, int n_in,
                              void* d_out, int out_size, void* d_ws, size_t ws_size,
                              hipStream_t stream) {
  const float* x = (const float*)d_in[0];
  const float* Wq = (const float*)d_in[1];
  const float* Wk = (const float*)d_in[2];
  const float* Wv = (const float*)d_in[3];
  const float* Wr = (const float*)d_in[4];
  const float* alpha = (const float*)d_in[5];
  const float* beta = (const float*)d_in[6];
  float* out = (float*)d_out;

  char* ws = (char*)d_ws;
  // ws layout (bytes): qkv 402,653,184 | Wt 1,572,864 | Wrs 16,777,216 | gq 64K | gk 64K
  u16* qkv = (u16*)ws;
  u16* Wt = (u16*)(ws + 402653184ull);
  u16* Wrs = (u16*)(ws + 402653184ull + 1572864ull);
  float* gq = (float*)(ws + 402653184ull + 1572864ull + 16777216ull);
  float* gk = gq + 16384;

  // x_bf16 scratch lives in d_out (268 MB; dead until gemm_out overwrites it)
  u16* xb = (u16*)d_out;

  hipMemsetAsync(gq, 0, 131072, stream);  // gq+gk
  convert_x<<<32768, 256, 0, stream>>>(x, xb);
  prep_w<<<1536, 256, 0, stream>>>(Wq, Wk, Wv, Wt);
  gemm_qkv<<<dim3(12, 1024), 256, 0, stream>>>(xb, Wt, qkv);
  pool_alpha<<<dim3(16, BATCH), 256, 0, stream>>>(qkv, alpha, gq);
  pool_beta<<<dim3(16, BATCH), 256, 0, stream>>>(qkv, beta, gq, gk);
  build_wrs<<<dim3(512, BATCH), 256, 0, stream>>>(Wr, gk, Wrs);
  gemm_out<<<dim3(4, 32, BATCH), 256, 0, stream>>>(qkv, Wrs, out);
}